// Round 8
// baseline (229.079 us; speedup 1.0000x reference)
//
#include <hip/hip_runtime.h>

using u16 = unsigned short;
using u32 = unsigned int;
using u64 = unsigned long long;

// Fixed problem shape (guarded in the launcher; generic fallback otherwise).
constexpr int Bc = 2, Tc = 8, Fc = 5, Mc = 128, Sc = 128;
constexpr int Np = 65536;         // points per (b,t) slab
constexpr int WPTS = 512;         // points per chunk
constexpr int NCH = Np / WPTS;    // 128 chunks per slab
constexpr int NBT = Bc * Tc;      // 16 slabs
constexpr int NBLK = 512;         // fused-kernel grid (co-resident by construction)
constexpr int MAX_ITEMS = NBT * Mc * NCH;

// Largest x with __fsqrt_rn(x) <= r (monotone correctly-rounded sqrt =>
// d2 <= sqrt_ub(r)  <=>  __fsqrt_rn(d2) <= r : the reference predicate, bit-exact).
__device__ __forceinline__ float sqrt_ub(float r) {
    float u = __fmul_rn(r, r);
    if (__fsqrt_rn(u) <= r) {
        while (true) {
            float nu = __uint_as_float(__float_as_uint(u) + 1u);
            if (__fsqrt_rn(nu) <= r) u = nu; else break;
        }
    } else {
        while (__fsqrt_rn(u) > r) u = __uint_as_float(__float_as_uint(u) - 1u);
    }
    return u;
}

__device__ __forceinline__ float box_radius(const float* __restrict__ box) {
    const float hl = __fmul_rn(0.5f, box[3]);
    const float hw = __fmul_rn(0.5f, box[4]);
    return __fmul_rn(__fsqrt_rn(__fadd_rn(__fmul_rn(hl, hl), __fmul_rn(hw, hw))), 1.1f);
}

// Device-wide barrier: all NBLK blocks are co-resident (capacity-checked).
// Release fence -> arrive -> spin on device-scope atomic -> acquire fence.
__device__ __forceinline__ void grid_barrier(int* bar, int target) {
    __syncthreads();
    __threadfence();                               // release my block's writes
    if (threadIdx.x == 0) {
        atomicAdd(bar, 1);
        while (atomicAdd(bar, 0) < target) __builtin_amdgcn_s_sleep(16);
    }
    __syncthreads();
    __threadfence();                               // acquire others' writes
}

// ---------------- fused kernel: count -> scan/worklist -> emit(+mirror) ------
__global__ __launch_bounds__(256, 2) void k_fused(
    const float* __restrict__ points,        // [B,T,N,F]
    const float* __restrict__ rois,          // [B,T,M,7]
    const int*   __restrict__ vlen,          // [B,T,M]
    int*  __restrict__ bar,                  // [0]=barrier (memset 0 per call)
    int*  __restrict__ counter,              // [0]=item count (memset 0)
    u16*  __restrict__ cnt,                  // [NBT*Mc][NCH]
    u32*  __restrict__ items,                // worklist
    float* __restrict__ out)                 // [B,M,T,S,F]
{
    __shared__ float4 stage4[4][WPTS * Fc / 4];    // 40KB: P3 wave-private staging
    __shared__ float sX[Mc], sY[Mc], sT[Mc];
    __shared__ int sAct[Mc];

    const int blk  = blockIdx.x;
    const int tid  = threadIdx.x;
    const int lane = tid & 63;
    const int wv   = tid >> 6;
    const u64 lt = (1ull << lane) - 1ull;

    // ================= P1: per-chunk hit counts (active boxes only) =========
    {
        const int bt  = blk & (NBT - 1);
        const int grp = blk >> 4;
        const int t   = bt & 7;
        if (tid < Mc) {
            const int act = (t == 0) || (vlen[bt * Mc + tid] != 0);
            sAct[tid] = act;
            if (act) {
                const float* box = rois + (size_t)(bt * Mc + tid) * 7;
                sX[tid] = box[0]; sY[tid] = box[1]; sT[tid] = sqrt_ub(box_radius(box));
            }
        }
        __syncthreads();

        const int chunk = grp * 4 + wv;
        const float* pc = points + ((size_t)bt * Np + (size_t)chunk * WPTS) * Fc;
        float px[8], py[8];
        #pragma unroll
        for (int h = 0; h < 2; ++h) {
            // lane owns 4 consecutive points: 4 pts x 5 floats = 5 float4s, coalesced
            const float4* src = (const float4*)(pc + (size_t)(h * 256 + lane * 4) * Fc);
            const float4 v0 = src[0], v1 = src[1], v2 = src[2], v3 = src[3], v4 = src[4];
            px[4*h+0] = v0.x; py[4*h+0] = v0.y;
            px[4*h+1] = v1.y; py[4*h+1] = v1.z;
            px[4*h+2] = v2.z; py[4*h+2] = v2.w;
            px[4*h+3] = v3.w; py[4*h+3] = v4.x;
        }
        u16* crow = cnt + (size_t)(bt * Mc) * NCH + chunk;
        for (int m = 0; m < Mc; ++m) {
            if (!sAct[m]) continue;                 // wave-uniform
            const float cx = sX[m], cy = sY[m], T = sT[m];
            int c = 0;
            #pragma unroll
            for (int k = 0; k < 8; ++k) {
                const float dx = __fsub_rn(px[k], cx);
                const float dy = __fsub_rn(py[k], cy);
                const float d2 = __fadd_rn(__fmul_rn(dx, dx), __fmul_rn(dy, dy));
                c += (int)__popcll(__ballot(d2 <= T));
            }
            if (lane == 0) crow[(size_t)m * NCH] = (u16)c;
        }
    }

    grid_barrier(bar, NBLK);

    // ================= P2: scan rows -> worklist; zero tails (+fallback) ====
    {
        const int row = blk * 4 + wv;               // bt*Mc + m, 2048 rows
        const int bt = row >> 7, m = row & (Mc - 1);
        const int t = bt & 7, b = bt >> 3;
        const bool active = (t == 0) || (vlen[row] != 0);
        if (active) {
            const u32 two = ((const u32*)(cnt + (size_t)row * NCH))[lane];
            const int a  = (int)(two & 0xFFFFu);
            const int a2 = (int)(two >> 16);
            const int s = a + a2;
            int incl = s;
            #pragma unroll
            for (int d = 1; d < 64; d <<= 1) { int v = __shfl_up(incl, d); if (lane >= d) incl += v; }
            const int excl = incl - s;              // base of chunk 2*lane
            const int tot  = __shfl(incl, 63);
            const int base2 = excl + a;             // base of chunk 2*lane+1

            const bool i1 = (a  > 0) && (excl  < Sc);
            const bool i2 = (a2 > 0) && (base2 < Sc);
            const u64 b1 = __ballot(i1);
            const u64 b2 = __ballot(i2);
            const int n1 = (int)__popcll(b1);
            const int total = n1 + (int)__popcll(b2);
            if (total > 0) {
                int pos0 = 0;
                if (lane == 0) pos0 = atomicAdd(counter, total);
                pos0 = __shfl(pos0, 0);
                // item = bt[4] | chunk[7] | m[7] | base[7]
                if (i1) items[pos0 + (int)__popcll(b1 & lt)] =
                    ((u32)bt << 21) | ((u32)(2 * lane) << 14) | ((u32)m << 7) | (u32)excl;
                if (i2) items[pos0 + n1 + (int)__popcll(b2 & lt)] =
                    ((u32)bt << 21) | ((u32)(2 * lane + 1) << 14) | ((u32)m << 7) | (u32)base2;
            }

            // zero own tail; frame-0 waves also zero fallback rows' tails
            const int fill = min(tot, Sc);
            float* ob = out + (size_t)((b * Mc + m) * Tc + t) * (Sc * Fc);
            for (int i = fill * Fc + lane; i < Sc * Fc; i += 64) ob[i] = 0.0f;
            if (t == 0) {
                for (int tp = 1; tp < Tc; ++tp) {
                    if (vlen[(b * Tc + tp) * Mc + m] == 0) {
                        float* of = out + (size_t)((b * Mc + m) * Tc + tp) * (Sc * Fc);
                        for (int i = fill * Fc + lane; i < Sc * Fc; i += 64) of[i] = 0.0f;
                    }
                }
            }
        }
    }

    grid_barrier(bar, 2 * NBLK);

    // ================= P3: emit winners (grid-stride waves over items) ======
    {
        const int n = counter[0];
        const int wid = blk * 4 + wv;
        float* L = (float*)stage4[wv];

        for (int i = wid; i < n; i += NBLK * 4) {
            const u32 it = items[i];
            const int base  = (int)(it & 127u);
            const int m     = (int)((it >> 7) & 127u);
            const int chunk = (int)((it >> 14) & 127u);
            const int bt    = (int)(it >> 21);
            const int t = bt & 7, b = bt >> 3;

            // fallback-row mask (frame-0 items also feed mirrored rows)
            u32 fb = 0;
            if (t == 0) {
                #pragma unroll
                for (int tp = 1; tp < Tc; ++tp)
                    if (vlen[(b * Tc + tp) * Mc + m] == 0) fb |= (1u << tp);
            }

            // stage full chunk (512 pts x 20B) into wave-private LDS, coalesced
            const float4* pc4 = (const float4*)(points + ((size_t)bt * Np + (size_t)chunk * WPTS) * Fc);
            #pragma unroll
            for (int q = 0; q < 10; ++q)
                ((float4*)L)[q * 64 + lane] = pc4[q * 64 + lane];

            const float* box = rois + (size_t)(bt * Mc + m) * 7;
            const float cx = box[0], cy = box[1];
            const float T = sqrt_ub(box_radius(box));
            float* orow = out + (size_t)((b * Mc + m) * Tc + t) * (Sc * Fc);

            int sb = base;
            #pragma unroll
            for (int g = 0; g < 8; ++g) {
                const int p = g * 64 + lane;
                const float qx = L[p * 5 + 0];
                const float qy = L[p * 5 + 1];
                const float dx = __fsub_rn(qx, cx);
                const float dy = __fsub_rn(qy, cy);
                const float d2 = __fadd_rn(__fmul_rn(dx, dx), __fmul_rn(dy, dy));
                const bool inside = (d2 <= T);
                const u64 bal = __ballot(inside);
                if (inside) {
                    const int slot = sb + (int)__popcll(bal & lt);
                    if (slot < Sc) {
                        const float f2 = L[p * 5 + 2], f3 = L[p * 5 + 3], f4 = L[p * 5 + 4];
                        float* o = orow + (size_t)slot * Fc;
                        o[0] = qx; o[1] = qy; o[2] = f2; o[3] = f3; o[4] = f4;
                        u32 fbm = fb;
                        while (fbm) {
                            const int tp = __ffs(fbm) - 1; fbm &= fbm - 1;
                            float* o2 = out + (size_t)((b * Mc + m) * Tc + tp) * (Sc * Fc)
                                            + (size_t)slot * Fc;
                            o2[0] = qx; o2[1] = qy; o2[2] = f2; o2[3] = f3; o2[4] = f4;
                        }
                    }
                }
                sb += (int)__popcll(bal);
            }
        }
    }
}

// ---------------- fallback: R2 single-kernel path (shape-generic) ------------
__global__ __launch_bounds__(1024) void vox_pool(
    const float* __restrict__ points, const float* __restrict__ rois,
    const int* __restrict__ valid_length, float* __restrict__ out,
    int N, int M, int S)
{
    const int blk = blockIdx.x;
    const int m = blk % M;
    const int t = (blk / M) % Tc;
    const int b = blk / (M * Tc);
    int t_eff = t;
    if (t != 0 && valid_length[(b * Tc + t) * M + m] == 0) t_eff = 0;
    const float* box = rois + (size_t)((b * Tc + t_eff) * M + m) * 7;
    const float cx = box[0], cy = box[1];
    const float r = box_radius(box);
    const float* pts = points + (size_t)(b * Tc + t_eff) * N * Fc;
    float* o = out + ((size_t)(b * M + m) * Tc + t) * (size_t)S * Fc;
    __shared__ int wcnt[16];
    const int tid = threadIdx.x, lane = tid & 63, wav = tid >> 6;
    const int nthreads = blockDim.x, nwaves = nthreads >> 6;
    int cnt = 0;
    for (int basei = 0; basei < N; basei += nthreads) {
        const int idx = basei + tid;
        bool inside = false;
        if (idx < N) {
            const float dx = __fsub_rn(pts[(size_t)idx * Fc + 0], cx);
            const float dy = __fsub_rn(pts[(size_t)idx * Fc + 1], cy);
            const float d2 = __fadd_rn(__fmul_rn(dx, dx), __fmul_rn(dy, dy));
            inside = (__fsqrt_rn(d2) <= r);
        }
        const unsigned long long bal = __ballot(inside);
        if (lane == 0) wcnt[wav] = __popcll(bal);
        __syncthreads();
        int wave_off = 0, block_tot = 0;
        for (int w = 0; w < nwaves; ++w) {
            const int c = wcnt[w];
            if (w < wav) wave_off += c;
            block_tot += c;
        }
        if (inside) {
            const int slot = cnt + wave_off + (int)__popcll(bal & ((1ull << lane) - 1ull));
            if (slot < S)
                for (int f = 0; f < Fc; ++f)
                    o[(size_t)slot * Fc + f] = pts[(size_t)idx * Fc + f];
        }
        cnt += block_tot;
        __syncthreads();
        if (cnt >= S) break;
    }
    const int filled = cnt < S ? cnt : S;
    for (int s = filled + tid; s < S; s += nthreads)
        for (int f = 0; f < Fc; ++f)
            o[(size_t)s * Fc + f] = 0.0f;
}

extern "C" void kernel_launch(void* const* d_in, const int* in_sizes, int n_in,
                              void* d_out, int out_size, void* d_ws, size_t ws_size,
                              hipStream_t stream) {
    const float* points = (const float*)d_in[0];
    const float* rois   = (const float*)d_in[1];
    const int*   vlen   = (const int*)d_in[2];
    float* out = (float*)d_out;

    const size_t ctl_bytes   = 128;                                  // bar + counter
    const size_t cnt_bytes   = (size_t)NBT * Mc * NCH * sizeof(u16); // 512 KiB
    const size_t items_bytes = (size_t)MAX_ITEMS * sizeof(u32);      // 1 MiB

    const bool fixed =
        in_sizes[0] == Bc * Tc * Np * Fc &&
        in_sizes[1] == Bc * Tc * Mc * 7 &&
        in_sizes[2] == Bc * Tc * Mc &&
        out_size    == Bc * Mc * Tc * Sc * Fc &&
        ws_size     >= ctl_bytes + cnt_bytes + items_bytes;

    if (fixed) {
        char* w = (char*)d_ws;
        int* bar     = (int*)w;
        int* counter = (int*)(w + 64);
        u16* cnt     = (u16*)(w + ctl_bytes);
        u32* items   = (u32*)(w + ctl_bytes + cnt_bytes);

        // zero barrier + item counter each call (graph-capturable memset node)
        hipMemsetAsync(w, 0, ctl_bytes, stream);
        k_fused<<<dim3(NBLK), 256, 0, stream>>>(points, rois, vlen, bar, counter, cnt, items, out);
    } else {
        const int N = in_sizes[0] / (Bc * Tc * Fc);
        const int M = in_sizes[2] / (Bc * Tc);
        const int S = out_size / (Bc * M * Tc * Fc);
        vox_pool<<<dim3(Bc * Tc * M), 1024, 0, stream>>>(points, rois, vlen, out, N, M, S);
    }
}

// Round 9
// 54.461 us; speedup vs baseline: 4.2063x; 4.2063x over previous
//
#include <hip/hip_runtime.h>

using u64 = unsigned long long;

// Fixed problem shape (guarded in the launcher; generic fallback otherwise).
constexpr int Bc = 2, Tc = 8, Fc = 5, Mc = 128, Sc = 128;
constexpr int Np = 65536;         // points per (b,t) slab
constexpr int WPTS = 512;         // points per wave-chunk
constexpr int NCH = Np / WPTS;    // 128 chunks per slab
constexpr int NR  = NCH / 4;      // 32 rounds (4 waves x 1 chunk per round)

// Largest x with __fsqrt_rn(x) <= r (monotone correctly-rounded sqrt =>
// d2 <= sqrt_ub(r)  <=>  __fsqrt_rn(d2) <= r : the reference predicate, bit-exact).
__device__ __forceinline__ float sqrt_ub(float r) {
    float u = __fmul_rn(r, r);
    if (__fsqrt_rn(u) <= r) {
        while (true) {
            float nu = __uint_as_float(__float_as_uint(u) + 1u);
            if (__fsqrt_rn(nu) <= r) u = nu; else break;
        }
    } else {
        while (__fsqrt_rn(u) > r) u = __uint_as_float(__float_as_uint(u) - 1u);
    }
    return u;
}

__device__ __forceinline__ float box_radius(const float* __restrict__ box) {
    const float hl = __fmul_rn(0.5f, box[3]);
    const float hw = __fmul_rn(0.5f, box[4]);
    return __fmul_rn(__fsqrt_rn(__fadd_rn(__fmul_rn(hl, hl), __fmul_rn(hw, hw))), 1.1f);
}

// One block per (b,t,m) box. 4 waves; per round each wave owns one 512-pt
// chunk: count via 8 ballots (masks kept in regs), one barrier, 4-entry
// prefix from LDS, winners emit from registers at exact slots. Early exit
// when cum >= S. Next round's xy is prefetched before the barrier; parity
// double-buffered wcnt keeps it to ONE barrier per round. All ordering is
// block-local: no cross-block dependencies, no workspace.
__global__ __launch_bounds__(256) void k_box(
    const float* __restrict__ points,        // [B,T,N,F]
    const float* __restrict__ rois,          // [B,T,M,7]
    const int*   __restrict__ vlen,          // [B,T,M]
    float*       __restrict__ out)           // [B,M,T,S,F]
{
    const int blk = blockIdx.x;
    const int m  = blk & (Mc - 1);           // low bits: 128 consecutive blocks share a slab
    const int bt = blk >> 7;
    const int t = bt & 7, b = bt >> 3;

    // fallback rows (t!=0, vlen==0) recompute the frame-0 pooling exactly
    int t_eff = t;
    if (t != 0 && vlen[bt * Mc + m] == 0) t_eff = 0;
    const int btE = b * Tc + t_eff;

    const float* box = rois + (size_t)(btE * Mc + m) * 7;
    const float cx = box[0], cy = box[1];
    const float T = sqrt_ub(box_radius(box));
    const float* pts = points + (size_t)btE * Np * Fc;
    float* orow = out + (size_t)((b * Mc + m) * Tc + t) * (Sc * Fc);

    __shared__ int wcnt[2][4];

    const int tid = threadIdx.x, lane = tid & 63, wv = tid >> 6;
    const u64 lt = (1ull << lane) - 1ull;

    // round-0 loads (xy only; strided dwords — the lines are pulled anyway)
    float px[8], py[8];
    {
        const int pbase = wv * WPTS;
        #pragma unroll
        for (int i = 0; i < 8; ++i) {
            const size_t idx = (size_t)(pbase + i * 64 + lane);
            px[i] = pts[idx * Fc + 0];
            py[i] = pts[idx * Fc + 1];
        }
    }

    int cum = 0;
    for (int r = 0; r < NR; ++r) {
        // ---- count my chunk; keep the 8 ballot masks for the emit step ----
        u64 bal[8];
        int c = 0;
        #pragma unroll
        for (int i = 0; i < 8; ++i) {
            const float dx = __fsub_rn(px[i], cx);
            const float dy = __fsub_rn(py[i], cy);
            const float d2 = __fadd_rn(__fmul_rn(dx, dx), __fmul_rn(dy, dy));
            bal[i] = __ballot(d2 <= T);
            c += (int)__popcll(bal[i]);
        }
        if (lane == 0) wcnt[r & 1][wv] = c;

        // ---- prefetch next round (latency hides under barrier + emit) ----
        float nx[8], ny[8];
        if (r + 1 < NR) {
            const int pbase = ((r + 1) * 4 + wv) * WPTS;
            #pragma unroll
            for (int i = 0; i < 8; ++i) {
                const size_t idx = (size_t)(pbase + i * 64 + lane);
                nx[i] = pts[idx * Fc + 0];
                ny[i] = pts[idx * Fc + 1];
            }
        }

        __syncthreads();                      // the single barrier per round
        const int c0 = wcnt[r & 1][0], c1 = wcnt[r & 1][1];
        const int c2 = wcnt[r & 1][2], c3 = wcnt[r & 1][3];
        int base = cum;
        if (wv > 0) base += c0;
        if (wv > 1) base += c1;
        if (wv > 2) base += c2;
        const int tot = c0 + c1 + c2 + c3;

        // ---- emit winners from registers (wave-uniform skip) ----
        if (base < Sc && c > 0) {
            const int pbase = (r * 4 + wv) * WPTS;
            int sb = base;
            #pragma unroll
            for (int i = 0; i < 8; ++i) {
                const bool inside = (bal[i] >> lane) & 1ull;
                if (inside) {
                    const int slot = sb + (int)__popcll(bal[i] & lt);
                    if (slot < Sc) {
                        const size_t idx = (size_t)(pbase + i * 64 + lane);
                        float* o = orow + (size_t)slot * Fc;
                        o[0] = px[i]; o[1] = py[i];
                        o[2] = pts[idx * Fc + 2];   // payload lines are L2-hot
                        o[3] = pts[idx * Fc + 3];
                        o[4] = pts[idx * Fc + 4];
                    }
                }
                sb += (int)__popcll(bal[i]);
            }
        }

        cum += tot;
        if (cum >= Sc) break;                 // block-uniform
        #pragma unroll
        for (int i = 0; i < 8; ++i) { px[i] = nx[i]; py[i] = ny[i]; }
        // parity double-buffer: round r+2 rewrites wcnt[r&1] only after every
        // wave passed barrier r+1, which follows its wcnt[r&1] reads. safe.
    }

    // ---- zero the tail slots [min(cum,S), S) ----
    const int fill = min(cum, Sc);
    for (int i = fill * Fc + tid; i < Sc * Fc; i += 256) orow[i] = 0.0f;
}

// ---------------- fallback: R2 single-kernel path (shape-generic) ------------
__global__ __launch_bounds__(1024) void vox_pool(
    const float* __restrict__ points, const float* __restrict__ rois,
    const int* __restrict__ valid_length, float* __restrict__ out,
    int N, int M, int S)
{
    const int blk = blockIdx.x;
    const int m = blk % M;
    const int t = (blk / M) % Tc;
    const int b = blk / (M * Tc);
    int t_eff = t;
    if (t != 0 && valid_length[(b * Tc + t) * M + m] == 0) t_eff = 0;
    const float* box = rois + (size_t)((b * Tc + t_eff) * M + m) * 7;
    const float cx = box[0], cy = box[1];
    const float r = box_radius(box);
    const float* pts = points + (size_t)(b * Tc + t_eff) * N * Fc;
    float* o = out + ((size_t)(b * M + m) * Tc + t) * (size_t)S * Fc;
    __shared__ int wcnt[16];
    const int tid = threadIdx.x, lane = tid & 63, wav = tid >> 6;
    const int nthreads = blockDim.x, nwaves = nthreads >> 6;
    int cnt = 0;
    for (int basei = 0; basei < N; basei += nthreads) {
        const int idx = basei + tid;
        bool inside = false;
        if (idx < N) {
            const float dx = __fsub_rn(pts[(size_t)idx * Fc + 0], cx);
            const float dy = __fsub_rn(pts[(size_t)idx * Fc + 1], cy);
            const float d2 = __fadd_rn(__fmul_rn(dx, dx), __fmul_rn(dy, dy));
            inside = (__fsqrt_rn(d2) <= r);
        }
        const unsigned long long bal = __ballot(inside);
        if (lane == 0) wcnt[wav] = __popcll(bal);
        __syncthreads();
        int wave_off = 0, block_tot = 0;
        for (int w = 0; w < nwaves; ++w) {
            const int c = wcnt[w];
            if (w < wav) wave_off += c;
            block_tot += c;
        }
        if (inside) {
            const int slot = cnt + wave_off + (int)__popcll(bal & ((1ull << lane) - 1ull));
            if (slot < S)
                for (int f = 0; f < Fc; ++f)
                    o[(size_t)slot * Fc + f] = pts[(size_t)idx * Fc + f];
        }
        cnt += block_tot;
        __syncthreads();
        if (cnt >= S) break;
    }
    const int filled = cnt < S ? cnt : S;
    for (int s = filled + tid; s < S; s += nthreads)
        for (int f = 0; f < Fc; ++f)
            o[(size_t)s * Fc + f] = 0.0f;
}

extern "C" void kernel_launch(void* const* d_in, const int* in_sizes, int n_in,
                              void* d_out, int out_size, void* d_ws, size_t ws_size,
                              hipStream_t stream) {
    const float* points = (const float*)d_in[0];
    const float* rois   = (const float*)d_in[1];
    const int*   vlen   = (const int*)d_in[2];
    float* out = (float*)d_out;

    const bool fixed =
        in_sizes[0] == Bc * Tc * Np * Fc &&
        in_sizes[1] == Bc * Tc * Mc * 7 &&
        in_sizes[2] == Bc * Tc * Mc &&
        out_size    == Bc * Mc * Tc * Sc * Fc;

    if (fixed) {
        k_box<<<dim3(Bc * Tc * Mc), 256, 0, stream>>>(points, rois, vlen, out);
    } else {
        const int N = in_sizes[0] / (Bc * Tc * Fc);
        const int M = in_sizes[2] / (Bc * Tc);
        const int S = out_size / (Bc * M * Tc * Fc);
        vox_pool<<<dim3(Bc * Tc * M), 1024, 0, stream>>>(points, rois, vlen, out, N, M, S);
    }
}